// Round 1
// 145.140 us; speedup vs baseline: 1.0079x; 1.0079x over previous
//
#include <hip/hip_runtime.h>
#include <math.h>

// Problem constants (from reference)
constexpr int   kS      = 7;
constexpr int   kNCls   = 20;
constexpr int   kB      = 16384;
constexpr int   kNCells = kB * kS * kS;          // 802,816
constexpr int   kNElems = kNCells * 30;          // 24,084,480 floats
constexpr float kWCoord = 5.0f;
constexpr float kWNoobj = 0.5f;
constexpr float kEps    = 1e-6f;

constexpr int kBlocks  = 2048;            // 8 blocks/CU on 256 CUs
constexpr int kThreads = 256;

// ---------------------------------------------------------------------------
// Wave-64 + LDS block reduce. Returns full block sum on thread 0.
// ---------------------------------------------------------------------------
__device__ __forceinline__ float block_reduce(float v) {
    #pragma unroll
    for (int off = 32; off > 0; off >>= 1)
        v += __shfl_down(v, off, 64);
    __shared__ float smem[kThreads / 64];
    const int lane = threadIdx.x & 63;
    const int wv   = threadIdx.x >> 6;
    if (lane == 0) smem[wv] = v;
    __syncthreads();
    float t = 0.0f;
    if (threadIdx.x == 0) {
        #pragma unroll
        for (int i = 0; i < kThreads / 64; ++i) t += smem[i];
    }
    return t;
}

// ---------------------------------------------------------------------------
// IoU between two center-format boxes (matches reference _iou exactly).
// ---------------------------------------------------------------------------
__device__ __forceinline__ float iou_f(float ax, float ay, float aw, float ah,
                                       float gx, float gy, float gw, float gh) {
    const float ax1 = ax - aw * 0.5f, ax2 = ax + aw * 0.5f;
    const float ay1 = ay - ah * 0.5f, ay2 = ay + ah * 0.5f;
    const float gx1 = gx - gw * 0.5f, gx2 = gx + gw * 0.5f;
    const float gy1 = gy - gh * 0.5f, gy2 = gy + gh * 0.5f;
    const float iw = fmaxf(0.0f, fminf(ax2, gx2) - fmaxf(ax1, gx1));
    const float ih = fmaxf(0.0f, fminf(ay2, gy2) - fmaxf(ay1, gy1));
    const float inter = iw * ih;
    const float uni = aw * ah + gw * gh - inter;
    return inter / (uni + kEps);
}

// ---------------------------------------------------------------------------
// Fused kernel.
// Part A (noobj): SELECTIVE strided reads — only channels 20,21 of each
//   30-float cell row (one aligned float2 at byte offset 80 of each 120B row).
//   Per 8 rows these 8B reads touch 8 distinct 64B lines out of 15, so HBM
//   fetch drops from 96.3 MB -> ~51.4 MB (64B TCC_EA granularity). Previous
//   version streamed all 30 channels and predicated 28 away.
// Part B: 64 labels per block on wave 0 (coalesced 24B rows, 15x float2 cell
//   gather). The gathered cells' ch20/21 lines are L3-warm from Part A.
// Finish: per-block partial -> plain store to partials[blockIdx.x].
//   NO same-address atomics: R4/R5/R6 showed 2048 single-address atomicAdds
//   pin the kernel at a constant ~60us (serialized cross-XCD coherence ops).
// ---------------------------------------------------------------------------
__global__ void __launch_bounds__(kThreads)
fused_kernel(const float* __restrict__ out,
             const float* __restrict__ labels,
             int nl,
             float* __restrict__ partials) {
    const int tid    = blockIdx.x * blockDim.x + threadIdx.x;
    const int stride = gridDim.x * blockDim.x;

    float dsum = 0.0f;

    // --- Part A: strided float2 reads of ch20/21 only ---
    // 802,816 cells over 524,288 threads: ~1.53 iters/thread. Two-deep manual
    // unroll keeps 2 independent loads in flight for the threads that get 2.
    // Index math kept in 32-bit: max element offset 24,084,470 < 2^31.
    {
        int i = tid;
        for (; i + stride < kNCells; i += 2 * stride) {
            const float2 a = *reinterpret_cast<const float2*>(out + i * 30 + 20);
            const float2 b = *reinterpret_cast<const float2*>(out + (i + stride) * 30 + 20);
            dsum += a.x * a.x + a.y * a.y + b.x * b.x + b.y * b.y;
        }
        for (; i < kNCells; i += stride) {
            const float2 a = *reinterpret_cast<const float2*>(out + i * 30 + 20);
            dsum += a.x * a.x + a.y * a.y;
        }
    }
    float sum = kWNoobj * dsum;

    // --- Part B: per-label terms, 64 labels per block (wave 0) ---
    const int lpb   = (nl + gridDim.x - 1) / gridDim.x;   // 64
    const int lbase = blockIdx.x * lpb;
    for (int j = threadIdx.x; j < lpb; j += blockDim.x) {
        const int l = lbase + j;
        if (l >= nl) break;

        const float2* lab2 = reinterpret_cast<const float2*>(labels + (size_t)l * 6);
        const float2 l0 = lab2[0];
        const float2 l1 = lab2[1];
        const float2 l2 = lab2[2];
        const int   c  = (int)l0.y;
        const float gx = l1.x, gy = l1.y, gw = l2.x, gh = l2.y;

        const float rowf = floorf(gx * (float)kS);
        const float colf = floorf(gy * (float)kS);
        const int row = (int)rowf;
        const int col = (int)colf;
        const int b   = (int)l0.x;

        // gather the 30-float cell (byte offset 120*cell, always 8B aligned)
        const float* p = out + ((size_t)b * (kS * kS) + row * kS + col) * 30;
        const float2* p2 = reinterpret_cast<const float2*>(p);
        float pv[30];
        #pragma unroll
        for (int j2 = 0; j2 < 15; ++j2) {
            const float2 t = p2[j2];
            pv[2 * j2]     = t.x;
            pv[2 * j2 + 1] = t.y;
        }

        // class loss
        float cl = 0.0f;
        #pragma unroll
        for (int j2 = 0; j2 < kNCls; ++j2) {
            const float d = pv[j2] - ((j2 == c) ? 1.0f : 0.0f);
            cl += d * d;
        }

        // IoUs (global coords: (rowf + x)/S, exact division like reference)
        const float g1x = (rowf + pv[22]) / (float)kS;
        const float g1y = (colf + pv[23]) / (float)kS;
        const float g2x = (rowf + pv[26]) / (float)kS;
        const float g2y = (colf + pv[27]) / (float)kS;

        const float iou1 = iou_f(g1x, g1y, pv[24], pv[25], gx, gy, gw, gh);
        const float iou2 = iou_f(g2x, g2y, pv[28], pv[29], gx, gy, gw, gh);
        const bool use1 = (iou1 >= iou2);

        // coord loss
        const float gtx_cell = gx * (float)kS - rowf;
        const float gty_cell = gy * (float)kS - colf;
        const float px = use1 ? pv[22] : pv[26];
        const float py = use1 ? pv[23] : pv[27];
        const float pw = use1 ? pv[24] : pv[28];
        const float ph = use1 ? pv[25] : pv[29];
        const float dx = px - gtx_cell;
        const float dy = py - gty_cell;
        const float dw = sqrtf(pw + kEps) - sqrtf(gw + kEps);
        const float dh = sqrtf(ph + kEps) - sqrtf(gh + kEps);
        const float coord = kWCoord * (dx * dx + dy * dy + dw * dw + dh * dh);

        // conf loss (per-label part)
        const float cp = use1 ? pv[20] : pv[21];
        const float ct = use1 ? iou1 : iou2;
        const float conf = (cp - ct) * (cp - ct) - kWNoobj * cp * cp;

        sum += cl + coord + conf;
    }

    const float bsum = block_reduce(sum);
    if (threadIdx.x == 0) partials[blockIdx.x] = bsum;
}

// ---------------------------------------------------------------------------
// Finalize: one block sums the 2048 per-block partials, divides by batch.
// ---------------------------------------------------------------------------
__global__ void __launch_bounds__(kThreads)
finalize_kernel(const float* __restrict__ partials, int n, float* __restrict__ out) {
    float s = 0.0f;
    for (int i = threadIdx.x; i < n; i += blockDim.x) s += partials[i];
    const float t = block_reduce(s);
    if (threadIdx.x == 0) out[0] = t * (1.0f / (float)kB);
}

extern "C" void kernel_launch(void* const* d_in, const int* in_sizes, int n_in,
                              void* d_out, int out_size, void* d_ws, size_t ws_size,
                              hipStream_t stream) {
    const float* output = (const float*)d_in[0];   // (B, 7, 7, 30) fp32
    const float* labels = (const float*)d_in[1];   // (NL, 6) fp32
    float* out = (float*)d_out;
    float* partials = (float*)d_ws;                // kBlocks floats, fully overwritten

    const int nl = in_sizes[1] / 6;                // 131072

    fused_kernel<<<kBlocks, kThreads, 0, stream>>>(output, labels, nl, partials);
    finalize_kernel<<<1, kThreads, 0, stream>>>(partials, kBlocks, out);
}

// Round 2
// 145.139 us; speedup vs baseline: 1.0080x; 1.0000x over previous
//
#include <hip/hip_runtime.h>
#include <math.h>

// Problem constants (from reference)
constexpr int   kS      = 7;
constexpr int   kNCls   = 20;
constexpr int   kB      = 16384;
constexpr int   kNCells = kB * kS * kS;          // 802,816
constexpr int   kNElems = kNCells * 30;          // 24,084,480 floats
constexpr float kWCoord = 5.0f;
constexpr float kWNoobj = 0.5f;
constexpr float kEps    = 1e-6f;

constexpr int kBlocks  = 2048;            // 8 blocks/CU on 256 CUs
constexpr int kThreads = 256;

// ---------------------------------------------------------------------------
// Wave-64 + LDS block reduce. Returns full block sum on thread 0.
// ---------------------------------------------------------------------------
__device__ __forceinline__ float block_reduce(float v) {
    #pragma unroll
    for (int off = 32; off > 0; off >>= 1)
        v += __shfl_down(v, off, 64);
    __shared__ float smem[kThreads / 64];
    const int lane = threadIdx.x & 63;
    const int wv   = threadIdx.x >> 6;
    if (lane == 0) smem[wv] = v;
    __syncthreads();
    float t = 0.0f;
    if (threadIdx.x == 0) {
        #pragma unroll
        for (int i = 0; i < kThreads / 64; ++i) t += smem[i];
    }
    return t;
}

// ---------------------------------------------------------------------------
// IoU between two center-format boxes (matches reference _iou exactly).
// ---------------------------------------------------------------------------
__device__ __forceinline__ float iou_f(float ax, float ay, float aw, float ah,
                                       float gx, float gy, float gw, float gh) {
    const float ax1 = ax - aw * 0.5f, ax2 = ax + aw * 0.5f;
    const float ay1 = ay - ah * 0.5f, ay2 = ay + ah * 0.5f;
    const float gx1 = gx - gw * 0.5f, gx2 = gx + gw * 0.5f;
    const float gy1 = gy - gh * 0.5f, gy2 = gy + gh * 0.5f;
    const float iw = fmaxf(0.0f, fminf(ax2, gx2) - fmaxf(ax1, gx1));
    const float ih = fmaxf(0.0f, fminf(ay2, gy2) - fmaxf(ay1, gy1));
    const float inter = iw * ih;
    const float uni = aw * ah + gw * gh - inter;
    return inter / (uni + kEps);
}

// ---------------------------------------------------------------------------
// Fused kernel — v2: gather-first overlap.
// R1 post-mortem: selective Part A reads were FETCH-neutral (>=128B HBM
//   granularity; ch20/21 chunks spaced 120B touch every sector). Fused floor
//   is ~96MB stream + latency tails.
// v2 structure: wave-0 threads load their label and ISSUE the 15 float2 cell
//   gathers BEFORE Part A's stream. Gather latency (2 miss rounds) hides
//   under ~15us of streaming; Part B becomes pure register math at the end.
//   pv[30] stays register-resident (static indices only — rule #20).
// Finish: per-block partial -> plain store. NO same-address atomics
//   (2048 serialized cross-XCD RMWs cost ~60us — prior session R4/R5/R6).
// ---------------------------------------------------------------------------
__global__ void __launch_bounds__(kThreads)
fused_kernel(const float* __restrict__ out,
             const float* __restrict__ labels,
             int nl,
             float* __restrict__ partials) {
    const int tid    = blockIdx.x * blockDim.x + threadIdx.x;
    const int stride = gridDim.x * blockDim.x;

    // --- Part B prologue: one label per wave-0 thread; issue gathers now ---
    const int lpb   = (nl + gridDim.x - 1) / gridDim.x;   // 64
    const int lbase = blockIdx.x * lpb;

    bool havelab = false;
    int   c = 0;
    float gx = 0.f, gy = 0.f, gw = 0.f, gh = 0.f;
    float rowf = 0.f, colf = 0.f;
    float pv[30];
    #pragma unroll
    for (int j2 = 0; j2 < 30; ++j2) pv[j2] = 0.0f;

    if (threadIdx.x < lpb) {
        const int l = lbase + threadIdx.x;
        if (l < nl) {
            havelab = true;
            const float2* lab2 = reinterpret_cast<const float2*>(labels + (size_t)l * 6);
            const float2 l0 = lab2[0];
            const float2 l1 = lab2[1];
            const float2 l2 = lab2[2];
            c  = (int)l0.y;
            gx = l1.x; gy = l1.y; gw = l2.x; gh = l2.y;

            rowf = floorf(gx * (float)kS);
            colf = floorf(gy * (float)kS);
            const int row = (int)rowf;
            const int col = (int)colf;
            const int b   = (int)l0.x;

            // gather the 30-float cell (120B rows, always 8B aligned)
            const float* p = out + ((size_t)b * (kS * kS) + row * kS + col) * 30;
            const float2* p2 = reinterpret_cast<const float2*>(p);
            #pragma unroll
            for (int j2 = 0; j2 < 15; ++j2) {
                const float2 t = p2[j2];
                pv[2 * j2]     = t.x;
                pv[2 * j2 + 1] = t.y;
            }
        }
    }

    // --- Part A: strided float2 reads of ch20/21; gathers in flight above ---
    float dsum = 0.0f;
    {
        int i = tid;
        for (; i + stride < kNCells; i += 2 * stride) {
            const float2 a = *reinterpret_cast<const float2*>(out + i * 30 + 20);
            const float2 b = *reinterpret_cast<const float2*>(out + (i + stride) * 30 + 20);
            dsum += a.x * a.x + a.y * a.y + b.x * b.x + b.y * b.y;
        }
        for (; i < kNCells; i += stride) {
            const float2 a = *reinterpret_cast<const float2*>(out + i * 30 + 20);
            dsum += a.x * a.x + a.y * a.y;
        }
    }
    float sum = kWNoobj * dsum;

    // --- Part B compute: pure register math, loads long since landed ---
    if (havelab) {
        // class loss
        float cl = 0.0f;
        #pragma unroll
        for (int j2 = 0; j2 < kNCls; ++j2) {
            const float d = pv[j2] - ((j2 == c) ? 1.0f : 0.0f);
            cl += d * d;
        }

        // IoUs (global coords: (rowf + x)/S, exact division like reference)
        const float g1x = (rowf + pv[22]) / (float)kS;
        const float g1y = (colf + pv[23]) / (float)kS;
        const float g2x = (rowf + pv[26]) / (float)kS;
        const float g2y = (colf + pv[27]) / (float)kS;

        const float iou1 = iou_f(g1x, g1y, pv[24], pv[25], gx, gy, gw, gh);
        const float iou2 = iou_f(g2x, g2y, pv[28], pv[29], gx, gy, gw, gh);
        const bool use1 = (iou1 >= iou2);

        // coord loss
        const float gtx_cell = gx * (float)kS - rowf;
        const float gty_cell = gy * (float)kS - colf;
        const float px = use1 ? pv[22] : pv[26];
        const float py = use1 ? pv[23] : pv[27];
        const float pw = use1 ? pv[24] : pv[28];
        const float ph = use1 ? pv[25] : pv[29];
        const float dx = px - gtx_cell;
        const float dy = py - gty_cell;
        const float dw = sqrtf(pw + kEps) - sqrtf(gw + kEps);
        const float dh = sqrtf(ph + kEps) - sqrtf(gh + kEps);
        const float coord = kWCoord * (dx * dx + dy * dy + dw * dw + dh * dh);

        // conf loss (per-label part)
        const float cp = use1 ? pv[20] : pv[21];
        const float ct = use1 ? iou1 : iou2;
        const float conf = (cp - ct) * (cp - ct) - kWNoobj * cp * cp;

        sum += cl + coord + conf;
    }

    // Generality fallback (empty for nl=131072, grid=2048): extra labels.
    for (int j = threadIdx.x + blockDim.x; j < lpb; j += blockDim.x) {
        const int l = lbase + j;
        if (l >= nl) break;
        const float2* lab2 = reinterpret_cast<const float2*>(labels + (size_t)l * 6);
        const float2 l0 = lab2[0];
        const float2 l1 = lab2[1];
        const float2 l2 = lab2[2];
        const int   cc  = (int)l1.x == 0 ? (int)l0.y : (int)l0.y;  // class
        const float ggx = l1.x, ggy = l1.y, ggw = l2.x, ggh = l2.y;
        const float rf = floorf(ggx * (float)kS);
        const float cf = floorf(ggy * (float)kS);
        const float* p = out + ((size_t)(int)l0.x * (kS * kS) + (int)rf * kS + (int)cf) * 30;
        const float2* p2 = reinterpret_cast<const float2*>(p);
        float qv[30];
        #pragma unroll
        for (int j2 = 0; j2 < 15; ++j2) {
            const float2 t = p2[j2];
            qv[2 * j2] = t.x; qv[2 * j2 + 1] = t.y;
        }
        float cl = 0.0f;
        #pragma unroll
        for (int j2 = 0; j2 < kNCls; ++j2) {
            const float d = qv[j2] - ((j2 == cc) ? 1.0f : 0.0f);
            cl += d * d;
        }
        const float g1x = (rf + qv[22]) / (float)kS;
        const float g1y = (cf + qv[23]) / (float)kS;
        const float g2x = (rf + qv[26]) / (float)kS;
        const float g2y = (cf + qv[27]) / (float)kS;
        const float iou1 = iou_f(g1x, g1y, qv[24], qv[25], ggx, ggy, ggw, ggh);
        const float iou2 = iou_f(g2x, g2y, qv[28], qv[29], ggx, ggy, ggw, ggh);
        const bool use1 = (iou1 >= iou2);
        const float gtx_cell = ggx * (float)kS - rf;
        const float gty_cell = ggy * (float)kS - cf;
        const float px = use1 ? qv[22] : qv[26];
        const float py = use1 ? qv[23] : qv[27];
        const float pw = use1 ? qv[24] : qv[28];
        const float ph = use1 ? qv[25] : qv[29];
        const float dx = px - gtx_cell;
        const float dy = py - gty_cell;
        const float dw = sqrtf(pw + kEps) - sqrtf(ggw + kEps);
        const float dh = sqrtf(ph + kEps) - sqrtf(ggh + kEps);
        const float coord = kWCoord * (dx * dx + dy * dy + dw * dw + dh * dh);
        const float cp = use1 ? qv[20] : qv[21];
        const float ct = use1 ? iou1 : iou2;
        sum += cl + coord + (cp - ct) * (cp - ct) - kWNoobj * cp * cp;
    }

    const float bsum = block_reduce(sum);
    if (threadIdx.x == 0) partials[blockIdx.x] = bsum;
}

// ---------------------------------------------------------------------------
// Finalize: one block sums the 2048 per-block partials, divides by batch.
// ---------------------------------------------------------------------------
__global__ void __launch_bounds__(kThreads)
finalize_kernel(const float* __restrict__ partials, int n, float* __restrict__ out) {
    float s = 0.0f;
    for (int i = threadIdx.x; i < n; i += blockDim.x) s += partials[i];
    const float t = block_reduce(s);
    if (threadIdx.x == 0) out[0] = t * (1.0f / (float)kB);
}

extern "C" void kernel_launch(void* const* d_in, const int* in_sizes, int n_in,
                              void* d_out, int out_size, void* d_ws, size_t ws_size,
                              hipStream_t stream) {
    const float* output = (const float*)d_in[0];   // (B, 7, 7, 30) fp32
    const float* labels = (const float*)d_in[1];   // (NL, 6) fp32
    float* out = (float*)d_out;
    float* partials = (float*)d_ws;                // kBlocks floats, fully overwritten

    const int nl = in_sizes[1] / 6;                // 131072

    fused_kernel<<<kBlocks, kThreads, 0, stream>>>(output, labels, nl, partials);
    finalize_kernel<<<1, kThreads, 0, stream>>>(partials, kBlocks, out);
}